// Round 1
// baseline (708.457 us; speedup 1.0000x reference)
//
#include <hip/hip_runtime.h>
#include <hip/hip_bf16.h>

// Problem constants
#define BB 64
#define TT 32768
#define KK 256
#define SS 16
#define LL 2065          // conv out length: (T + 2K - K)/S + 1
#define PP 2048          // T/S output frames
#define LT1 32           // l-values per K1 block
#define NLT 65           // ceil(L/32)
#define NPART (BB*NLT)   // 4160 partial-sum slots per channel
#define PT 256           // p-values per K3 block
#define HROWS (PT+15)    // 271 h rows staged per K3 block

// ---------------- Kernel 1: forward conv + scale/bias/relu + BN partials ----------------
// h[b,o,l] = relu(cs[o]*(sum_k w[o,k]*x[b, l*16+k-256] + cb[o]))
// w[o,k] = conv_w[o,k]*(gate+1)/2.  Stored bf16 as h[b][l][o] (channel-contiguous).
__global__ __launch_bounds__(256, 2)
void k1_conv_fwd(const float* __restrict__ x, const float* __restrict__ cw,
                 const float* __restrict__ cb, const float* __restrict__ cgt,
                 const float* __restrict__ cs,
                 __hip_bfloat16* __restrict__ hout,
                 float* __restrict__ psum, float* __restrict__ psq)
{
    __shared__ float w_s[64*257];                 // 64 ch x 256 taps, +1 pad (2-way banks)
    __shared__ __align__(16) float xs2[16*48];    // x window transposed [kr][m], m<47
    __shared__ float redS[4][64];
    __shared__ float redQ[4][64];

    const int tid = threadIdx.x;
    const int cgb = blockIdx.x;   // channel group 0..3 (64 ch each)
    const int lt  = blockIdx.y;   // l tile 0..64
    const int b   = blockIdx.z;   // batch
    const int c0  = cgb*64;
    const int l0  = lt*LT1;

    // stage gated weights
    for (int i = tid; i < 64*256; i += 256) {
        int cl = i >> 8, k = i & 255;
        int gi = (c0 + cl)*KK + k;
        w_s[cl*257 + k] = cw[gi] * (cgt[gi] + 1.0f) * 0.5f;
    }
    // stage x window: 752 = 47*16 values, zero-padded at edges
    const int pos0 = l0*SS - KK;
    for (int i = tid; i < 752; i += 256) {
        int m = i >> 4, kr = i & 15;
        int pos = pos0 + i;
        xs2[kr*48 + m] = (pos >= 0 && pos < TT) ? x[b*TT + pos] : 0.0f;
    }
    __syncthreads();

    const int o  = tid & 63;      // local channel (wave-varying)
    const int jg = tid >> 6;      // l-group (wave-uniform)

    float acc[8];
    #pragma unroll
    for (int j = 0; j < 8; ++j) acc[j] = 0.0f;

    #pragma unroll 1
    for (int kr = 0; kr < 16; ++kr) {
        // x values for rows jg*8 .. jg*8+23 at phase kr (broadcast reads)
        float xv[24];
        const float4* xb = (const float4*)&xs2[kr*48 + jg*8];
        #pragma unroll
        for (int q = 0; q < 6; ++q) {
            float4 t4 = xb[q];
            xv[q*4+0] = t4.x; xv[q*4+1] = t4.y; xv[q*4+2] = t4.z; xv[q*4+3] = t4.w;
        }
        #pragma unroll
        for (int kq = 0; kq < 16; ++kq) {
            float wv = w_s[o*257 + kq*16 + kr];   // tap k = kq*16 + kr
            #pragma unroll
            for (int jj = 0; jj < 8; ++jj)
                acc[jj] = fmaf(wv, xv[jj + kq], acc[jj]);
        }
    }

    const int c = c0 + o;
    const float scale = cs[c], bias = cb[c];
    float lsum = 0.0f, lsq = 0.0f;
    #pragma unroll
    for (int jj = 0; jj < 8; ++jj) {
        int l = l0 + jg*8 + jj;
        if (l < LL) {
            float hv = fmaxf(scale*(acc[jj] + bias), 0.0f);
            hout[(size_t)(b*LL + l)*KK + c] = __float2bfloat16(hv);
            lsum += hv; lsq += hv*hv;
        }
    }
    redS[jg][o] = lsum; redQ[jg][o] = lsq;
    __syncthreads();
    if (jg == 0) {
        float s = redS[0][o]+redS[1][o]+redS[2][o]+redS[3][o];
        float q = redQ[0][o]+redQ[1][o]+redQ[2][o]+redQ[3][o];
        int pi = b*NLT + lt;
        psum[c*NPART + pi] = s;
        psq [c*NPART + pi] = q;
    }
}

// ---------------- Kernel 2: BN stats + folded transposed-conv weights ----------------
// Per channel c: mu, var over B*L; a = gamma*rsigma; bc = beta - mu*a.
// W3T[k][c] = ct_scale * a * wt[c][k] where wt = ct_w*(ct_gate+1)/2.
// SWS[c][r] = sum_d wt[c][16d+r] * bc   (for the position-independent constant).
__global__ __launch_bounds__(256)
void k2_bn_stats(const float* __restrict__ psum, const float* __restrict__ psq,
                 const float* __restrict__ bng, const float* __restrict__ bnb,
                 const float* __restrict__ ctw, const float* __restrict__ ctg,
                 const float* __restrict__ ctscale,
                 float* __restrict__ W3T, float* __restrict__ SWS)
{
    __shared__ double rs[4], rq[4];
    __shared__ float s_a, s_bc;
    __shared__ float swl[256];
    const int c = blockIdx.x;
    const int tid = threadIdx.x;
    double s = 0.0, q = 0.0;
    for (int i = tid; i < NPART; i += 256) {
        s += (double)psum[c*NPART + i];
        q += (double)psq [c*NPART + i];
    }
    for (int off = 32; off > 0; off >>= 1) {
        s += __shfl_down(s, off);
        q += __shfl_down(q, off);
    }
    if ((tid & 63) == 0) { rs[tid >> 6] = s; rq[tid >> 6] = q; }
    __syncthreads();
    if (tid == 0) {
        double st = rs[0]+rs[1]+rs[2]+rs[3];
        double qt = rq[0]+rq[1]+rq[2]+rq[3];
        const double cnt = (double)BB * (double)LL;
        double mu = st / cnt;
        double var = qt / cnt - mu*mu;
        float rsig = (float)(1.0 / sqrt(var + 1e-5));
        float a = bng[c] * rsig;
        s_a = a;
        s_bc = bnb[c] - (float)mu * a;
    }
    __syncthreads();
    float a = s_a, bc = s_bc, scl = ctscale[0];
    int gi = c*KK + tid;                           // k = tid
    float wt = ctw[gi] * (ctg[gi] + 1.0f) * 0.5f;
    W3T[tid*KK + c] = scl * a * wt;
    swl[tid] = wt * bc;
    __syncthreads();
    if (tid < 16) {
        float acc2 = 0.0f;
        #pragma unroll
        for (int d = 0; d < 16; ++d) acc2 += swl[d*16 + tid];
        SWS[c*16 + tid] = acc2;
    }
}

// ---------------- Kernel 2b: finalize per-phase constants ----------------
__global__ void k2b_const(const float* __restrict__ SWS, const float* __restrict__ ctb,
                          const float* __restrict__ ctscale, float* __restrict__ C2)
{
    int r = threadIdx.x;
    if (r < 16) {
        float s = 0.0f;
        for (int c = 0; c < 256; ++c) s += SWS[c*16 + r];
        C2[r] = ctscale[0] * (s + ctb[0]);
    }
}

// ---------------- Kernel 3: transposed conv (BN folded into W3T/C2) ----------------
// out[b, 16p+r] = C2[r] + sum_{c,d} W3T[16d+r][c] * h[b][p+16-d][c]
__global__ __launch_bounds__(256, 2)
void k3_convt(const __hip_bfloat16* __restrict__ h, const float* __restrict__ W3T,
              const float* __restrict__ C2, float* __restrict__ out)
{
    __shared__ __align__(16) float w3_s[256*36];     // [k][c-chunk] padded 32->36
    __shared__ __align__(16) float h_s[HROWS*36];    // [row][c-chunk] padded

    const int tid  = threadIdx.x;
    const int pt   = blockIdx.x;   // 0..7
    const int b    = blockIdx.y;   // 0..63
    const int p0   = pt*PT;
    const int l0r  = p0 + 1;       // first h row needed
    const int rg   = tid & 3;
    const int psub = tid >> 2;     // 0..63

    float acc[4][4];
    #pragma unroll
    for (int jp = 0; jp < 4; ++jp)
        #pragma unroll
        for (int jr = 0; jr < 4; ++jr) acc[jp][jr] = 0.0f;

    for (int cc = 0; cc < 8; ++cc) {
        __syncthreads();
        for (int i = tid; i < 256*32; i += 256) {
            int k = i >> 5, cl = i & 31;
            w3_s[k*36 + cl] = W3T[k*KK + cc*32 + cl];
        }
        for (int i = tid; i < HROWS*32; i += 256) {
            int row = i >> 5, cl = i & 31;
            h_s[row*36 + cl] =
                __bfloat162float(h[(size_t)(b*LL + l0r + row)*KK + cc*32 + cl]);
        }
        __syncthreads();

        #pragma unroll 1
        for (int d = 0; d < 16; ++d) {
            #pragma unroll
            for (int c4 = 0; c4 < 8; ++c4) {
                float4 hv[4], wv[4];
                #pragma unroll
                for (int jp = 0; jp < 4; ++jp)
                    hv[jp] = *(const float4*)&h_s[(psub + 64*jp + 15 - d)*36 + c4*4];
                #pragma unroll
                for (int jr = 0; jr < 4; ++jr)
                    wv[jr] = *(const float4*)&w3_s[(16*d + rg + 4*jr)*36 + c4*4];
                #pragma unroll
                for (int jp = 0; jp < 4; ++jp)
                    #pragma unroll
                    for (int jr = 0; jr < 4; ++jr) {
                        acc[jp][jr] = fmaf(hv[jp].x, wv[jr].x, acc[jp][jr]);
                        acc[jp][jr] = fmaf(hv[jp].y, wv[jr].y, acc[jp][jr]);
                        acc[jp][jr] = fmaf(hv[jp].z, wv[jr].z, acc[jp][jr]);
                        acc[jp][jr] = fmaf(hv[jp].w, wv[jr].w, acc[jp][jr]);
                    }
            }
        }
    }

    #pragma unroll
    for (int jr = 0; jr < 4; ++jr) {
        float c2 = C2[rg + 4*jr];
        #pragma unroll
        for (int jp = 0; jp < 4; ++jp) {
            int p = p0 + psub + 64*jp;
            out[(size_t)b*TT + p*16 + rg + 4*jr] = acc[jp][jr] + c2;
        }
    }
}

extern "C" void kernel_launch(void* const* d_in, const int* in_sizes, int n_in,
                              void* d_out, int out_size, void* d_ws, size_t ws_size,
                              hipStream_t stream)
{
    const float* x       = (const float*)d_in[0];
    const float* cw      = (const float*)d_in[1];
    const float* cb      = (const float*)d_in[2];
    const float* cgt     = (const float*)d_in[3];
    const float* cs      = (const float*)d_in[4];
    const float* bng     = (const float*)d_in[5];
    const float* bnb     = (const float*)d_in[6];
    const float* ctw     = (const float*)d_in[7];
    const float* ctb     = (const float*)d_in[8];
    const float* ctg     = (const float*)d_in[9];
    const float* ctscale = (const float*)d_in[10];
    float* out = (float*)d_out;

    // workspace layout (~76.5 MB total)
    char* ws = (char*)d_ws;
    __hip_bfloat16* h = (__hip_bfloat16*)ws;
    size_t off = (size_t)BB*LL*KK*2;                         // 67,665,920
    float* psum = (float*)(ws + off); off += (size_t)KK*NPART*4;
    float* psq  = (float*)(ws + off); off += (size_t)KK*NPART*4;
    float* W3T  = (float*)(ws + off); off += (size_t)KK*KK*4;
    float* SWS  = (float*)(ws + off); off += (size_t)KK*16*4;
    float* C2   = (float*)(ws + off); off += 64;

    k1_conv_fwd<<<dim3(4, NLT, BB), 256, 0, stream>>>(x, cw, cb, cgt, cs, h, psum, psq);
    k2_bn_stats<<<dim3(KK), 256, 0, stream>>>(psum, psq, bng, bnb, ctw, ctg, ctscale, W3T, SWS);
    k2b_const<<<dim3(1), 64, 0, stream>>>(SWS, ctb, ctscale, C2);
    k3_convt<<<dim3(PP/PT, BB), 256, 0, stream>>>(h, W3T, C2, out);
}

// Round 2
// 258.284 us; speedup vs baseline: 2.7429x; 2.7429x over previous
//
#include <hip/hip_runtime.h>
#include <hip/hip_bf16.h>

#define BB 64
#define TT 32768
#define KK 256
#define LL 2065          // conv out length
#define NLT 9            // l-tiles of 256 per batch
#define NPART (BB*NLT)   // 576 partial slots per channel
#define NJ 19            // j-range for synthesis (P4 packing)

typedef __attribute__((ext_vector_type(8))) short short8;
typedef __attribute__((ext_vector_type(4))) float f32x4;
typedef __attribute__((ext_vector_type(4))) int int4v;

__device__ __forceinline__ unsigned short f2bf(float f) {
    unsigned u = __builtin_bit_cast(unsigned, f);
    unsigned r = (u + 0x7FFFu + ((u >> 16) & 1u)) >> 16;
    return (unsigned short)r;
}

// ---------------- k0: gated conv weights -> MFMA B-fragment-linear bf16 ----------------
// W1f[half][kk(8)][ntL(8)][lane(64)][i(8)] ; o = half*128+ntL*16+(lane&15), k = kk*32+(lane>>4)*8+i
__global__ void k0_w1f(const float* __restrict__ cw, const float* __restrict__ cgt,
                       unsigned short* __restrict__ W1f)
{
    int idx = blockIdx.x*256 + threadIdx.x;        // 8192 threads, 8 elems each
    int lane = idx & 63, ntL = (idx>>6)&7, kk = (idx>>9)&7, half = idx>>12;
    int o = half*128 + ntL*16 + (lane&15);
    int kbase = kk*32 + ((lane>>4)<<3);
    short8 v;
    #pragma unroll
    for (int i = 0; i < 8; ++i) {
        int gi = o*KK + kbase + i;
        v[i] = (short)f2bf(cw[gi]*(cgt[gi]+1.0f)*0.5f);
    }
    *(short8*)(W1f + (size_t)idx*8) = v;
}

// ---------------- k1: analysis conv (MFMA) + scale/bias/relu + bf16 h + BN partials ----
// h[b][l][c], block = 256 l x 128 c (half), 4 waves (64 l each), K=256 in 8 kk-steps.
__global__ __launch_bounds__(256, 2)
void k1_conv(const float* __restrict__ x, const float* __restrict__ cs,
             const float* __restrict__ cb, const unsigned short* __restrict__ W1f,
             unsigned short* __restrict__ hout,
             float* __restrict__ psum, float* __restrict__ psq)
{
    __shared__ __align__(16) char smem[13056 + 65536];
    char* xwinb = smem;                      // padded bf16 x-window (13056 B)
    char* wbuf  = smem + 13056;              // W1f half (65536 B)
    float* redS = (float*)smem;              // alias (used after K-loop)
    float* redQ = (float*)(smem + 2048);

    const int tid   = threadIdx.x;
    const int half  = blockIdx.x & 1;
    const int ltile = blockIdx.x >> 1;
    const int b     = blockIdx.y;
    const int l0    = ltile * 256;
    const long pos0 = (long)l0*16 - 256;
    const int lane  = tid & 63;
    const int w     = tid >> 6;

    // stage W1f half (64 KB, reg-staged, linear)
    {
        const int4v* src = (const int4v*)(W1f + (size_t)half*32768);
        int4v* dst = (int4v*)wbuf;
        #pragma unroll 4
        for (int it = 0; it < 16; ++it)
            dst[it*256 + tid] = src[it*256 + tid];
    }
    // stage x window: 272 groups of 16 elems; group g at bytes 48g..48g+31 (pad 8/16)
    {
        const float* xs = x + (size_t)b*TT;
        for (int g = tid; g < 272; g += 256) {
            unsigned uu[8];
            #pragma unroll
            for (int m = 0; m < 16; m += 2) {
                long p = pos0 + g*16 + m;
                float f0 = (p   >= 0 && p   < TT) ? xs[p]   : 0.0f;
                float f1 = (p+1 >= 0 && p+1 < TT) ? xs[p+1] : 0.0f;
                uu[m>>1] = (unsigned)f2bf(f0) | ((unsigned)f2bf(f1) << 16);
            }
            int4v w0 = { (int)uu[0], (int)uu[1], (int)uu[2], (int)uu[3] };
            int4v w1 = { (int)uu[4], (int)uu[5], (int)uu[6], (int)uu[7] };
            *(int4v*)(xwinb + 48*g)      = w0;
            *(int4v*)(xwinb + 48*g + 16) = w1;
        }
    }
    __syncthreads();

    // K-loop: barrier-free, all LDS-resident
    f32x4 acc[4][8];
    #pragma unroll
    for (int mt = 0; mt < 4; ++mt)
        #pragma unroll
        for (int nt = 0; nt < 8; ++nt) acc[mt][nt] = (f32x4){0.f,0.f,0.f,0.f};

    const int gq = lane >> 4;
    const int Gt = 16*gq + 16*(gq>>1);                 // {0,16,48,64}
    const int abase = 48*((w<<6) + (lane & 15)) + Gt;  // + 768*mt + 96*kk

    #pragma unroll
    for (int kk = 0; kk < 8; ++kk) {
        short8 af[4];
        #pragma unroll
        for (int mt = 0; mt < 4; ++mt)
            af[mt] = *(const short8*)(xwinb + abase + mt*768 + kk*96);
        #pragma unroll
        for (int nt = 0; nt < 8; ++nt) {
            short8 bfr = *(const short8*)(wbuf + (kk*8 + nt)*1024 + lane*16);
            #pragma unroll
            for (int mt = 0; mt < 4; ++mt)
                acc[mt][nt] = __builtin_amdgcn_mfma_f32_16x16x32_bf16(af[mt], bfr, acc[mt][nt], 0, 0, 0);
        }
    }
    __syncthreads();   // protect redS alias over xwin

    // epilogue: scale/bias/relu, bf16 store, per-channel partial sums
    const int c0   = half*128;
    const int colc = lane & 15;
    const int rgrp = lane >> 4;
    for (int nt = 0; nt < 8; ++nt) {
        int c = c0 + nt*16 + colc;
        float sc = cs[c], bi = cb[c];
        float s = 0.f, q = 0.f;
        #pragma unroll
        for (int mt = 0; mt < 4; ++mt) {
            int lbase = l0 + (w<<6) + mt*16 + rgrp*4;
            #pragma unroll
            for (int r = 0; r < 4; ++r) {
                int l = lbase + r;
                if (l < LL) {
                    float hv = fmaxf(sc*(acc[mt][nt][r] + bi), 0.0f);
                    hout[(size_t)(b*LL + l)*KK + c] = f2bf(hv);
                    s += hv; q += hv*hv;
                }
            }
        }
        s += __shfl_xor(s, 16); s += __shfl_xor(s, 32);
        q += __shfl_xor(q, 16); q += __shfl_xor(q, 32);
        if (lane < 16) {
            redS[w*128 + nt*16 + lane] = s;
            redQ[w*128 + nt*16 + lane] = q;
        }
    }
    __syncthreads();
    if (tid < 128) {
        float s = redS[tid] + redS[128+tid] + redS[256+tid] + redS[384+tid];
        float q = redQ[tid] + redQ[128+tid] + redQ[256+tid] + redQ[384+tid];
        int c = c0 + tid;
        int slot = b*NLT + ltile;
        psum[c*NPART + slot] = s;
        psq [c*NPART + slot] = q;
    }
}

// ---------------- k2: BN stats -> folded synthesis weights W3s[k][c] + SWS ----------------
__global__ __launch_bounds__(256)
void k2_bn(const float* __restrict__ psum, const float* __restrict__ psq,
           const float* __restrict__ bng, const float* __restrict__ bnb,
           const float* __restrict__ ctw, const float* __restrict__ ctg,
           const float* __restrict__ ctscale,
           float* __restrict__ W3s, float* __restrict__ SWS)
{
    __shared__ double rs[4], rq[4];
    __shared__ float s_a, s_bc;
    __shared__ float swl[256];
    const int c = blockIdx.x;
    const int tid = threadIdx.x;
    double s = 0.0, q = 0.0;
    for (int i = tid; i < NPART; i += 256) {
        s += (double)psum[c*NPART + i];
        q += (double)psq [c*NPART + i];
    }
    for (int off = 32; off > 0; off >>= 1) {
        s += __shfl_down(s, off);
        q += __shfl_down(q, off);
    }
    if ((tid & 63) == 0) { rs[tid >> 6] = s; rq[tid >> 6] = q; }
    __syncthreads();
    if (tid == 0) {
        double st = rs[0]+rs[1]+rs[2]+rs[3];
        double qt = rq[0]+rq[1]+rq[2]+rq[3];
        const double cnt = (double)BB * (double)LL;
        double mu = st / cnt;
        double var = qt / cnt - mu*mu;
        float rsig = (float)(1.0 / sqrt(var + 1e-5));
        float a = bng[c] * rsig;
        s_a = a;
        s_bc = bnb[c] - (float)mu * a;
    }
    __syncthreads();
    float a = s_a, bc = s_bc, scl = ctscale[0];
    int gi = c*KK + tid;                          // k = tid
    float wt = ctw[gi] * (ctg[gi] + 1.0f) * 0.5f;
    W3s[tid*KK + c] = scl * a * wt;
    swl[tid] = wt * bc;
    __syncthreads();
    if (tid < 16) {
        float acc2 = 0.0f;
        #pragma unroll
        for (int d = 0; d < 16; ++d) acc2 += swl[d*16 + tid];
        SWS[c*16 + tid] = acc2;
    }
}

__global__ void k2b_const(const float* __restrict__ SWS, const float* __restrict__ ctb,
                          const float* __restrict__ ctscale, float* __restrict__ C2)
{
    int r = threadIdx.x;
    if (r < 16) {
        float s = 0.0f;
        for (int c = 0; c < 256; ++c) s += SWS[c*16 + r];
        C2[r] = ctscale[0] * (s + ctb[0]);
    }
}

// ---------------- k2c: B2f fragment table for synthesis ----------------
// B2f[((j*8+kk)*4+ntG)*64+lane][i] ; u = ntG*16+(lane&15) = (pr,r), c = kk*32+(lane>>4)*8+i
// value = (0 <= pr+15-j <= 15) ? W3s[16*(pr+15-j) + r][c] : 0
__global__ void k2c_b2f(const float* __restrict__ W3s, unsigned short* __restrict__ B2f)
{
    int idx = blockIdx.x*256 + threadIdx.x;        // 38912 threads
    int lane = idx & 63;
    int ntG  = (idx>>6) & 3;
    int kk   = (idx>>8) & 7;
    int j    = idx>>11;
    int c    = kk*32 + ((lane>>4)<<3);
    int r    = lane & 15;
    int d    = ntG + 15 - j;
    short8 v;
    if (d >= 0 && d <= 15) {
        const float* wr = W3s + (size_t)(16*d + r)*KK + c;
        #pragma unroll
        for (int i = 0; i < 8; ++i) v[i] = (short)f2bf(wr[i]);
    } else {
        #pragma unroll
        for (int i = 0; i < 8; ++i) v[i] = 0;
    }
    *(short8*)(B2f + (size_t)idx*8) = v;
}

// ---------------- k3: synthesis conv (MFMA), N=64 packed output ----------------
// out[b][64*P+u] = C2[u&15] + sum_{j,c} h[b][4P+1+j][c] * B2[(j,c)][u]
// block = 64 P x 64 u, waves 2x2 (wave = 32P x 32u = 2mt x 2nt), 512 blocks.
__global__ __launch_bounds__(256, 2)
void k3_synth(const unsigned short* __restrict__ h, const unsigned short* __restrict__ B2f,
              const float* __restrict__ C2, float* __restrict__ out)
{
    __shared__ __align__(16) char Ab[32768];      // 64 rows x 512 B, c-block XOR (row&7)
    const int tid  = threadIdx.x;
    const int b    = blockIdx.x >> 3;
    const int P0   = (blockIdx.x & 7) * 64;
    const int lane = tid & 63;
    const int w    = tid >> 6;
    const int wq   = (w >> 1) * 32;
    const int wu   = (w & 1) * 32;

    f32x4 acc[2][2];
    #pragma unroll
    for (int mt = 0; mt < 2; ++mt)
        #pragma unroll
        for (int nt = 0; nt < 2; ++nt) acc[mt][nt] = (f32x4){0.f,0.f,0.f,0.f};

    const float c2v = C2[lane & 15];
    const int srow = tid >> 5;        // 0..7
    const int sblk = tid & 31;

    for (int j = 0; j < NJ; ++j) {
        __syncthreads();
        // stage 64 rows (l = 4*(P0+row)+1+j), swizzled c-blocks
        #pragma unroll
        for (int it = 0; it < 8; ++it) {
            int row = it*8 + srow;
            const int4v* src = (const int4v*)(h + ((size_t)(b*LL + 4*(P0+row) + 1 + j) << 8)) + sblk;
            int4v v = *src;
            *(int4v*)(Ab + row*512 + ((sblk ^ (row & 7)) << 4)) = v;
        }
        __syncthreads();
        #pragma unroll
        for (int kk = 0; kk < 8; ++kk) {
            short8 af[2], bfr[2];
            #pragma unroll
            for (int mt = 0; mt < 2; ++mt) {
                int row = wq + mt*16 + (lane & 15);
                int blk = kk*4 + (lane >> 4);
                af[mt] = *(const short8*)(Ab + row*512 + ((blk ^ (row & 7)) << 4));
            }
            #pragma unroll
            for (int nt = 0; nt < 2; ++nt) {
                int ntG = (wu >> 4) + nt;
                bfr[nt] = *(const short8*)(B2f + (((size_t)(j*8 + kk)*4 + ntG)*64 + lane)*8);
            }
            #pragma unroll
            for (int mt = 0; mt < 2; ++mt)
                #pragma unroll
                for (int nt = 0; nt < 2; ++nt)
                    acc[mt][nt] = __builtin_amdgcn_mfma_f32_16x16x32_bf16(af[mt], bfr[nt], acc[mt][nt], 0, 0, 0);
        }
    }

    #pragma unroll
    for (int mt = 0; mt < 2; ++mt)
        #pragma unroll
        for (int nt = 0; nt < 2; ++nt)
            #pragma unroll
            for (int r = 0; r < 4; ++r) {
                int P = P0 + wq + mt*16 + (lane >> 4)*4 + r;
                int u = wu + nt*16 + (lane & 15);
                out[(size_t)b*TT + P*64 + u] = acc[mt][nt][r] + c2v;
            }
}

extern "C" void kernel_launch(void* const* d_in, const int* in_sizes, int n_in,
                              void* d_out, int out_size, void* d_ws, size_t ws_size,
                              hipStream_t stream)
{
    const float* x       = (const float*)d_in[0];
    const float* cw      = (const float*)d_in[1];
    const float* cb      = (const float*)d_in[2];
    const float* cgt     = (const float*)d_in[3];
    const float* cs      = (const float*)d_in[4];
    const float* bng     = (const float*)d_in[5];
    const float* bnb     = (const float*)d_in[6];
    const float* ctw     = (const float*)d_in[7];
    const float* ctb     = (const float*)d_in[8];
    const float* ctg     = (const float*)d_in[9];
    const float* ctscale = (const float*)d_in[10];
    float* out = (float*)d_out;

    char* ws = (char*)d_ws;
    size_t off = 0;
    unsigned short* h    = (unsigned short*)(ws + off); off += (size_t)BB*LL*KK*2;   // 67,665,920
    float* psum          = (float*)(ws + off);          off += (size_t)KK*NPART*4;   // 589,824
    float* psq           = (float*)(ws + off);          off += (size_t)KK*NPART*4;
    unsigned short* W1f  = (unsigned short*)(ws + off); off += 65536*2;              // 131,072
    float* W3s           = (float*)(ws + off);          off += (size_t)KK*KK*4;      // 262,144
    float* SWS           = (float*)(ws + off);          off += (size_t)KK*16*4;      // 16,384
    float* C2            = (float*)(ws + off);          off += 64;
    unsigned short* B2f  = (unsigned short*)(ws + off); off += (size_t)NJ*8*4*64*8*2; // 622,592

    k0_w1f  <<<32, 256, 0, stream>>>(cw, cgt, W1f);
    k1_conv <<<dim3(18, BB), 256, 0, stream>>>(x, cs, cb, W1f, h, psum, psq);
    k2_bn   <<<KK, 256, 0, stream>>>(psum, psq, bng, bnb, ctw, ctg, ctscale, W3s, SWS);
    k2b_const<<<1, 64, 0, stream>>>(SWS, ctb, ctscale, C2);
    k2c_b2f <<<152, 256, 0, stream>>>(W3s, B2f);
    k3_synth<<<512, 256, 0, stream>>>(h, B2f, C2, out);
}

// Round 3
// 140.218 us; speedup vs baseline: 5.0525x; 1.8420x over previous
//
#include <hip/hip_runtime.h>
#include <hip/hip_bf16.h>

#define BB 64
#define TT 32768
#define KK 256
#define LL 2065          // conv out length
#define NLT 9            // l-tiles of 256 per batch
#define NPART (BB*NLT)   // 576 partial slots per channel
#define NJ 19            // j-range for synthesis (P4 packing)
#define HSTR 144         // k1 epilogue LDS row stride (ushorts): 288B, 16B-aligned, conflict-free

typedef __attribute__((ext_vector_type(8))) short short8;
typedef __attribute__((ext_vector_type(4))) float f32x4;
typedef __attribute__((ext_vector_type(4))) int int4v;

__device__ __forceinline__ unsigned short f2bf(float f) {
    unsigned u = __builtin_bit_cast(unsigned, f);
    unsigned r = (u + 0x7FFFu + ((u >> 16) & 1u)) >> 16;
    return (unsigned short)r;
}

// ---------------- k0: gated conv weights -> MFMA B-fragment-linear bf16 ----------------
__global__ void k0_w1f(const float* __restrict__ cw, const float* __restrict__ cgt,
                       unsigned short* __restrict__ W1f)
{
    int idx = blockIdx.x*256 + threadIdx.x;        // 8192 threads, 8 elems each
    int lane = idx & 63, ntL = (idx>>6)&7, kk = (idx>>9)&7, half = idx>>12;
    int o = half*128 + ntL*16 + (lane&15);
    int kbase = kk*32 + ((lane>>4)<<3);
    short8 v;
    #pragma unroll
    for (int i = 0; i < 8; ++i) {
        int gi = o*KK + kbase + i;
        v[i] = (short)f2bf(cw[gi]*(cgt[gi]+1.0f)*0.5f);
    }
    *(short8*)(W1f + (size_t)idx*8) = v;
}

// ---------------- k1: analysis conv (MFMA) + scale/bias/relu + bf16 h + BN partials ----
__global__ __launch_bounds__(256, 2)
void k1_conv(const float* __restrict__ x, const float* __restrict__ cs,
             const float* __restrict__ cb, const unsigned short* __restrict__ W1f,
             unsigned short* __restrict__ hout,
             float* __restrict__ psum, float* __restrict__ psq)
{
    __shared__ __align__(16) char smem[13056 + 65536];   // 78592 B
    char* xwinb = smem;                      // padded bf16 x-window (13056 B)
    char* wbuf  = smem + 13056;              // W1f half (65536 B)
    // epilogue aliases (valid after K-loop barrier):
    unsigned short* hb = (unsigned short*)smem;          // 256 x HSTR ushorts = 73728 B
    float* redS = (float*)(smem + 73728);                // 512 floats
    float* redQ = (float*)(smem + 73728 + 2048);         // needs 77824 <= 78592 OK

    const int tid   = threadIdx.x;
    const int half  = blockIdx.x & 1;
    const int ltile = blockIdx.x >> 1;
    const int b     = blockIdx.y;
    const int l0    = ltile * 256;
    const long pos0 = (long)l0*16 - 256;
    const int lane  = tid & 63;
    const int w     = tid >> 6;

    // stage W1f half (64 KB, reg-staged, linear)
    {
        const int4v* src = (const int4v*)(W1f + (size_t)half*32768);
        int4v* dst = (int4v*)wbuf;
        #pragma unroll 4
        for (int it = 0; it < 16; ++it)
            dst[it*256 + tid] = src[it*256 + tid];
    }
    // stage x window: 272 groups of 16 elems; group g at bytes 48g..48g+31
    {
        const float* xs = x + (size_t)b*TT;
        for (int g = tid; g < 272; g += 256) {
            unsigned uu[8];
            #pragma unroll
            for (int m = 0; m < 16; m += 2) {
                long p = pos0 + g*16 + m;
                float f0 = (p   >= 0 && p   < TT) ? xs[p]   : 0.0f;
                float f1 = (p+1 >= 0 && p+1 < TT) ? xs[p+1] : 0.0f;
                uu[m>>1] = (unsigned)f2bf(f0) | ((unsigned)f2bf(f1) << 16);
            }
            int4v w0 = { (int)uu[0], (int)uu[1], (int)uu[2], (int)uu[3] };
            int4v w1 = { (int)uu[4], (int)uu[5], (int)uu[6], (int)uu[7] };
            *(int4v*)(xwinb + 48*g)      = w0;
            *(int4v*)(xwinb + 48*g + 16) = w1;
        }
    }
    __syncthreads();

    // K-loop: barrier-free, all LDS-resident
    f32x4 acc[4][8];
    #pragma unroll
    for (int mt = 0; mt < 4; ++mt)
        #pragma unroll
        for (int nt = 0; nt < 8; ++nt) acc[mt][nt] = (f32x4){0.f,0.f,0.f,0.f};

    const int gq = lane >> 4;
    const int Gt = 16*gq + 16*(gq>>1);                 // {0,16,48,64}
    const int abase = 48*((w<<6) + (lane & 15)) + Gt;  // + 768*mt + 96*kk

    #pragma unroll
    for (int kk = 0; kk < 8; ++kk) {
        short8 af[4];
        #pragma unroll
        for (int mt = 0; mt < 4; ++mt)
            af[mt] = *(const short8*)(xwinb + abase + mt*768 + kk*96);
        #pragma unroll
        for (int nt = 0; nt < 8; ++nt) {
            short8 bfr = *(const short8*)(wbuf + (kk*8 + nt)*1024 + lane*16);
            #pragma unroll
            for (int mt = 0; mt < 4; ++mt)
                acc[mt][nt] = __builtin_amdgcn_mfma_f32_16x16x32_bf16(af[mt], bfr, acc[mt][nt], 0, 0, 0);
        }
    }
    __syncthreads();   // xwin/wbuf dead; smem re-used as hb/redS/redQ

    // epilogue: scale/bias/relu -> LDS bf16 tile + per-channel partial sums
    const int c0   = half*128;
    const int colc = lane & 15;
    const int rgrp = lane >> 4;
    for (int nt = 0; nt < 8; ++nt) {
        int c = c0 + nt*16 + colc;
        float sc = cs[c], bi = cb[c];
        float s = 0.f, q = 0.f;
        #pragma unroll
        for (int mt = 0; mt < 4; ++mt) {
            int rowb = (w<<6) + mt*16 + rgrp*4;
            #pragma unroll
            for (int r = 0; r < 4; ++r) {
                float hv = fmaxf(sc*(acc[mt][nt][r] + bi), 0.0f);
                hb[(rowb + r)*HSTR + nt*16 + colc] = f2bf(hv);
                if (l0 + rowb + r < LL) { s += hv; q += hv*hv; }
            }
        }
        s += __shfl_xor(s, 16); s += __shfl_xor(s, 32);
        q += __shfl_xor(q, 16); q += __shfl_xor(q, 32);
        if (lane < 16) {
            redS[w*128 + nt*16 + lane] = s;
            redQ[w*128 + nt*16 + lane] = q;
        }
    }
    __syncthreads();

    // coalesced h write: 16 lanes x 16B per row (256B row-half), full 64B lines
    {
        const int rsub = tid >> 4;       // 0..15
        const int cpos = tid & 15;       // 16B chunk within row-half
        #pragma unroll
        for (int it = 0; it < 16; ++it) {
            int row = it*16 + rsub;
            int l = l0 + row;
            if (l < LL) {
                int4v v = *(const int4v*)(hb + row*HSTR + cpos*8);
                *(int4v*)(hout + (((size_t)(b*LL + l)) << 8) + half*128 + cpos*8) = v;
            }
        }
    }
    if (tid < 128) {
        float s = redS[tid] + redS[128+tid] + redS[256+tid] + redS[384+tid];
        float q = redQ[tid] + redQ[128+tid] + redQ[256+tid] + redQ[384+tid];
        int c = c0 + tid;
        int slot = b*NLT + ltile;
        psum[c*NPART + slot] = s;
        psq [c*NPART + slot] = q;
    }
}

// ---------------- k2: BN stats -> folded synthesis weights W3s[k][c] + SWS ----------------
__global__ __launch_bounds__(256)
void k2_bn(const float* __restrict__ psum, const float* __restrict__ psq,
           const float* __restrict__ bng, const float* __restrict__ bnb,
           const float* __restrict__ ctw, const float* __restrict__ ctg,
           const float* __restrict__ ctscale,
           float* __restrict__ W3s, float* __restrict__ SWS)
{
    __shared__ double rs[4], rq[4];
    __shared__ float s_a, s_bc;
    __shared__ float swl[256];
    const int c = blockIdx.x;
    const int tid = threadIdx.x;
    double s = 0.0, q = 0.0;
    for (int i = tid; i < NPART; i += 256) {
        s += (double)psum[c*NPART + i];
        q += (double)psq [c*NPART + i];
    }
    for (int off = 32; off > 0; off >>= 1) {
        s += __shfl_down(s, off);
        q += __shfl_down(q, off);
    }
    if ((tid & 63) == 0) { rs[tid >> 6] = s; rq[tid >> 6] = q; }
    __syncthreads();
    if (tid == 0) {
        double st = rs[0]+rs[1]+rs[2]+rs[3];
        double qt = rq[0]+rq[1]+rq[2]+rq[3];
        const double cnt = (double)BB * (double)LL;
        double mu = st / cnt;
        double var = qt / cnt - mu*mu;
        float rsig = (float)(1.0 / sqrt(var + 1e-5));
        float a = bng[c] * rsig;
        s_a = a;
        s_bc = bnb[c] - (float)mu * a;
    }
    __syncthreads();
    float a = s_a, bc = s_bc, scl = ctscale[0];
    int gi = c*KK + tid;                          // k = tid
    float wt = ctw[gi] * (ctg[gi] + 1.0f) * 0.5f;
    W3s[tid*KK + c] = scl * a * wt;
    swl[tid] = wt * bc;
    __syncthreads();
    if (tid < 16) {
        float acc2 = 0.0f;
        #pragma unroll
        for (int d = 0; d < 16; ++d) acc2 += swl[d*16 + tid];
        SWS[c*16 + tid] = acc2;
    }
}

__global__ void k2b_const(const float* __restrict__ SWS, const float* __restrict__ ctb,
                          const float* __restrict__ ctscale, float* __restrict__ C2)
{
    int r = threadIdx.x;
    if (r < 16) {
        float s = 0.0f;
        for (int c = 0; c < 256; ++c) s += SWS[c*16 + r];
        C2[r] = ctscale[0] * (s + ctb[0]);
    }
}

// ---------------- k2c: B2f fragment table for synthesis ----------------
__global__ void k2c_b2f(const float* __restrict__ W3s, unsigned short* __restrict__ B2f)
{
    int idx = blockIdx.x*256 + threadIdx.x;        // 38912 threads
    int lane = idx & 63;
    int ntG  = (idx>>6) & 3;
    int kk   = (idx>>8) & 7;
    int j    = idx>>11;
    int c    = kk*32 + ((lane>>4)<<3);
    int r    = lane & 15;
    int d    = ntG + 15 - j;
    short8 v;
    if (d >= 0 && d <= 15) {
        const float* wr = W3s + (size_t)(16*d + r)*KK + c;
        #pragma unroll
        for (int i = 0; i < 8; ++i) v[i] = (short)f2bf(wr[i]);
    } else {
        #pragma unroll
        for (int i = 0; i < 8; ++i) v[i] = 0;
    }
    *(short8*)(B2f + (size_t)idx*8) = v;
}

// ---------------- k3: synthesis conv (MFMA), 2-phase double-buffered pipeline ----------
// out[b][64*P+u] = C2[u&15] + sum_{j,c} h[b][4P+1+j][c] * B2[(j,c)][u]
__global__ __launch_bounds__(256, 2)
void k3_synth(const unsigned short* __restrict__ h, const unsigned short* __restrict__ B2f,
              const float* __restrict__ C2, float* __restrict__ out)
{
    __shared__ __align__(16) char Ab[2][32768];   // 64 rows x 512 B each, XOR(row&7) swizzle
    const int tid  = threadIdx.x;
    const int b    = blockIdx.x >> 3;
    const int P0   = (blockIdx.x & 7) * 64;
    const int lane = tid & 63;
    const int w    = tid >> 6;
    const int wq   = (w >> 1) * 32;
    const int wu   = (w & 1) * 32;
    const int srow = tid >> 5;        // 0..7
    const int sblk = tid & 31;

    const unsigned short* hbase = h + ((size_t)(b*LL) << 8);

    f32x4 acc[2][2];
    #pragma unroll
    for (int mt = 0; mt < 2; ++mt)
        #pragma unroll
        for (int nt = 0; nt < 2; ++nt) acc[mt][nt] = (f32x4){0.f,0.f,0.f,0.f};

    int4v st[8];
    // prologue: load+write j=0 into buf0
    #pragma unroll
    for (int it = 0; it < 8; ++it) {
        int row = it*8 + srow;
        st[it] = *((const int4v*)(hbase + ((size_t)(4*(P0+row) + 1) << 8)) + sblk);
    }
    #pragma unroll
    for (int it = 0; it < 8; ++it) {
        int row = it*8 + srow;
        *(int4v*)(Ab[0] + row*512 + ((sblk ^ srow) << 4)) = st[it];
    }

    int cur = 0;
    for (int j = 0; j < NJ; ++j) {
        // issue next-j global loads (stay in flight across the barrier)
        if (j + 1 < NJ) {
            #pragma unroll
            for (int it = 0; it < 8; ++it) {
                int row = it*8 + srow;
                st[it] = *((const int4v*)(hbase + ((size_t)(4*(P0+row) + 2 + j) << 8)) + sblk);
            }
        }
        asm volatile("s_waitcnt lgkmcnt(0)" ::: "memory");  // my ds_writes visible
        __builtin_amdgcn_s_barrier();                        // all waves' writes visible

        const char* buf = Ab[cur];
        #pragma unroll
        for (int kk = 0; kk < 8; ++kk) {
            short8 af[2], bfr[2];
            #pragma unroll
            for (int mt = 0; mt < 2; ++mt) {
                int row = wq + mt*16 + (lane & 15);
                int blk = kk*4 + (lane >> 4);
                af[mt] = *(const short8*)(buf + row*512 + ((blk ^ (row & 7)) << 4));
            }
            #pragma unroll
            for (int nt = 0; nt < 2; ++nt) {
                int ntG = (wu >> 4) + nt;
                bfr[nt] = *(const short8*)(B2f + (((size_t)(j*8 + kk)*4 + ntG)*64 + lane)*8);
            }
            #pragma unroll
            for (int mt = 0; mt < 2; ++mt)
                #pragma unroll
                for (int nt = 0; nt < 2; ++nt)
                    acc[mt][nt] = __builtin_amdgcn_mfma_f32_16x16x32_bf16(af[mt], bfr[nt], acc[mt][nt], 0, 0, 0);
        }

        if (j + 1 < NJ) {
            asm volatile("s_waitcnt vmcnt(0)" ::: "memory"); // next-j loads arrived
            char* nb = Ab[cur ^ 1];
            #pragma unroll
            for (int it = 0; it < 8; ++it) {
                int row = it*8 + srow;
                *(int4v*)(nb + row*512 + ((sblk ^ srow) << 4)) = st[it];
            }
        }
        cur ^= 1;
    }

    const float c2v = C2[lane & 15];
    #pragma unroll
    for (int mt = 0; mt < 2; ++mt)
        #pragma unroll
        for (int nt = 0; nt < 2; ++nt)
            #pragma unroll
            for (int r = 0; r < 4; ++r) {
                int P = P0 + wq + mt*16 + (lane >> 4)*4 + r;
                int u = wu + nt*16 + (lane & 15);
                out[(size_t)b*TT + P*64 + u] = acc[mt][nt][r] + c2v;
            }
}

extern "C" void kernel_launch(void* const* d_in, const int* in_sizes, int n_in,
                              void* d_out, int out_size, void* d_ws, size_t ws_size,
                              hipStream_t stream)
{
    const float* x       = (const float*)d_in[0];
    const float* cw      = (const float*)d_in[1];
    const float* cb      = (const float*)d_in[2];
    const float* cgt     = (const float*)d_in[3];
    const float* cs      = (const float*)d_in[4];
    const float* bng     = (const float*)d_in[5];
    const float* bnb     = (const float*)d_in[6];
    const float* ctw     = (const float*)d_in[7];
    const float* ctb     = (const float*)d_in[8];
    const float* ctg     = (const float*)d_in[9];
    const float* ctscale = (const float*)d_in[10];
    float* out = (float*)d_out;

    char* ws = (char*)d_ws;
    size_t off = 0;
    unsigned short* h    = (unsigned short*)(ws + off); off += (size_t)BB*LL*KK*2;   // 67,665,920
    float* psum          = (float*)(ws + off);          off += (size_t)KK*NPART*4;
    float* psq           = (float*)(ws + off);          off += (size_t)KK*NPART*4;
    unsigned short* W1f  = (unsigned short*)(ws + off); off += 65536*2;
    float* W3s           = (float*)(ws + off);          off += (size_t)KK*KK*4;
    float* SWS           = (float*)(ws + off);          off += (size_t)KK*16*4;
    float* C2            = (float*)(ws + off);          off += 64;
    unsigned short* B2f  = (unsigned short*)(ws + off); off += (size_t)NJ*8*4*64*8*2;

    k0_w1f  <<<32, 256, 0, stream>>>(cw, cgt, W1f);
    k1_conv <<<dim3(18, BB), 256, 0, stream>>>(x, cs, cb, W1f, h, psum, psq);
    k2_bn   <<<KK, 256, 0, stream>>>(psum, psq, bng, bnb, ctw, ctg, ctscale, W3s, SWS);
    k2b_const<<<1, 64, 0, stream>>>(SWS, ctb, ctscale, C2);
    k2c_b2f <<<152, 256, 0, stream>>>(W3s, B2f);
    k3_synth<<<512, 256, 0, stream>>>(h, B2f, C2, out);
}

// Round 6
// 124.083 us; speedup vs baseline: 5.7095x; 1.1300x over previous
//
#include <hip/hip_runtime.h>
#include <hip/hip_bf16.h>

#define BB 64
#define TT 32768
#define KK 256
#define LL 2065          // conv out length
#define NLT 9            // l-tiles of 256 per batch
#define NPART (BB*NLT)   // 576 partial slots per channel
#define NJ 19            // j-range for synthesis (P4 packing)
#define HBSTR 132        // k1 epilogue LDS row stride in ushorts (264 B)
#define NPT 8            // k3 P-tiles per batch: (TT/64)/64

typedef __attribute__((ext_vector_type(8))) short short8;
typedef __attribute__((ext_vector_type(4))) float f32x4;
typedef __attribute__((ext_vector_type(4))) int int4v;
typedef __attribute__((ext_vector_type(2))) unsigned int uint2v;

__device__ __forceinline__ unsigned short f2bf(float f) {
    unsigned u = __builtin_bit_cast(unsigned, f);
    unsigned r = (u + 0x7FFFu + ((u >> 16) & 1u)) >> 16;
    return (unsigned short)r;
}

// ---------------- k0: gated conv weights -> MFMA fragment-linear bf16 ----------------
__global__ void k0_w1f(const float* __restrict__ cw, const float* __restrict__ cgt,
                       unsigned short* __restrict__ W1f)
{
    int idx = blockIdx.x*256 + threadIdx.x;        // 8192 threads, 8 elems each
    int lane = idx & 63, ntL = (idx>>6)&7, kk = (idx>>9)&7, half = idx>>12;
    int o = half*128 + ntL*16 + (lane&15);
    int kbase = kk*32 + ((lane>>4)<<3);
    short8 v;
    #pragma unroll
    for (int i = 0; i < 8; ++i) {
        int gi = o*KK + kbase + i;
        v[i] = (short)f2bf(cw[gi]*(cgt[gi]+1.0f)*0.5f);
    }
    *(short8*)(W1f + (size_t)idx*8) = v;
}

// ---------------- k1: analysis conv (MFMA, swapped operands) ----------------
// acc holds h^T: lane owns c-quad (M-dim=c) at one l (N-dim=l).
__global__ __launch_bounds__(256, 2)
void k1_conv(const float* __restrict__ x, const float* __restrict__ cs,
             const float* __restrict__ cb, const unsigned short* __restrict__ W1f,
             unsigned short* __restrict__ hout,
             float* __restrict__ psum, float* __restrict__ psq)
{
    __shared__ __align__(16) char smem[13056 + 65536];   // 78592 B
    char* xwinb = smem;                      // padded bf16 x-window (13056 B)
    char* wbuf  = smem + 13056;              // W1f half (65536 B)
    // epilogue aliases:
    unsigned short* hb = (unsigned short*)smem;          // 256 x HBSTR ushorts = 67584 B
    float* redS = (float*)(smem + 67584);                // [4w][8mt][4g][4rr] = 2048 B
    float* redQ = (float*)(smem + 67584 + 2048);         // 71680 <= 78592 OK

    const int tid   = threadIdx.x;
    const int half  = blockIdx.x & 1;
    const int ltile = blockIdx.x >> 1;
    const int b     = blockIdx.y;
    const int l0    = ltile * 256;
    const long pos0 = (long)l0*16 - 256;
    const int lane  = tid & 63;
    const int w     = tid >> 6;

    // stage W1f half (64 KB)
    {
        const int4v* src = (const int4v*)(W1f + (size_t)half*32768);
        int4v* dst = (int4v*)wbuf;
        #pragma unroll 4
        for (int it = 0; it < 16; ++it)
            dst[it*256 + tid] = src[it*256 + tid];
    }
    // stage x window: 272 groups of 16 elems; group g at bytes 48g..48g+31
    {
        const float* xs = x + (size_t)b*TT;
        for (int g = tid; g < 272; g += 256) {
            unsigned uu[8];
            #pragma unroll
            for (int m = 0; m < 16; m += 2) {
                long p = pos0 + g*16 + m;
                float f0 = (p   >= 0 && p   < TT) ? xs[p]   : 0.0f;
                float f1 = (p+1 >= 0 && p+1 < TT) ? xs[p+1] : 0.0f;
                uu[m>>1] = (unsigned)f2bf(f0) | ((unsigned)f2bf(f1) << 16);
            }
            int4v w0 = { (int)uu[0], (int)uu[1], (int)uu[2], (int)uu[3] };
            int4v w1 = { (int)uu[4], (int)uu[5], (int)uu[6], (int)uu[7] };
            *(int4v*)(xwinb + 48*g)      = w0;
            *(int4v*)(xwinb + 48*g + 16) = w1;
        }
    }
    __syncthreads();

    // K-loop: barrier-free. acc[mt=c-group 0..7][nt=l-group 0..3]
    f32x4 acc[8][4];
    #pragma unroll
    for (int mt = 0; mt < 8; ++mt)
        #pragma unroll
        for (int nt = 0; nt < 4; ++nt) acc[mt][nt] = (f32x4){0.f,0.f,0.f,0.f};

    const int gq = lane >> 4;
    const int Gt = 16*gq + 16*(gq>>1);                 // {0,16,48,64}
    const int abase = 48*((w<<6) + (lane & 15)) + Gt;  // + 768*nt + 96*kk

    #pragma unroll
    for (int kk = 0; kk < 8; ++kk) {
        short8 bfx[4];
        #pragma unroll
        for (int nt = 0; nt < 4; ++nt)
            bfx[nt] = *(const short8*)(xwinb + abase + nt*768 + kk*96);
        #pragma unroll
        for (int mt = 0; mt < 8; ++mt) {
            short8 afw = *(const short8*)(wbuf + (kk*8 + mt)*1024 + lane*16);
            #pragma unroll
            for (int nt = 0; nt < 4; ++nt)
                acc[mt][nt] = __builtin_amdgcn_mfma_f32_16x16x32_bf16(afw, bfx[nt], acc[mt][nt], 0, 0, 0);
        }
    }
    __syncthreads();   // xwin/wbuf dead; smem re-used as hb/redS/redQ

    // epilogue: scale/bias/relu; lane holds c-quad at one l -> b64 LDS writes
    const int c0 = half*128;
    const int g  = lane >> 4;
    const int li = lane & 15;
    for (int mt = 0; mt < 8; ++mt) {
        int cq = c0 + mt*16 + g*4;
        f32x4 cs4 = *(const f32x4*)&cs[cq];
        f32x4 cb4 = *(const f32x4*)&cb[cq];
        f32x4 s4 = (f32x4){0.f,0.f,0.f,0.f};
        f32x4 q4 = (f32x4){0.f,0.f,0.f,0.f};
        #pragma unroll
        for (int nt = 0; nt < 4; ++nt) {
            int lloc = (w<<6) + nt*16 + li;
            f32x4 hv;
            #pragma unroll
            for (int rr = 0; rr < 4; ++rr)
                hv[rr] = fmaxf(cs4[rr]*(acc[mt][nt][rr] + cb4[rr]), 0.0f);
            unsigned lo = (unsigned)f2bf(hv[0]) | ((unsigned)f2bf(hv[1]) << 16);
            unsigned hi = (unsigned)f2bf(hv[2]) | ((unsigned)f2bf(hv[3]) << 16);
            uint2v pk = { lo, hi };
            *(uint2v*)(hb + lloc*HBSTR + mt*16 + g*4) = pk;
            if (l0 + lloc < LL) { s4 += hv; q4 += hv*hv; }
        }
        #pragma unroll
        for (int d = 1; d < 16; d <<= 1) {
            #pragma unroll
            for (int rr = 0; rr < 4; ++rr) {
                s4[rr] += __shfl_xor(s4[rr], d);
                q4[rr] += __shfl_xor(q4[rr], d);
            }
        }
        if (li == 0) {
            *(f32x4*)&redS[((w*8 + mt)*4 + g)*4] = s4;
            *(f32x4*)&redQ[((w*8 + mt)*4 + g)*4] = q4;
        }
    }
    __syncthreads();

    // coalesced h write: 16 lanes x 16B per row-half (256 B)
    {
        const int rsub = tid >> 4;       // 0..15
        const int cpos = tid & 15;
        #pragma unroll
        for (int it = 0; it < 16; ++it) {
            int row = it*16 + rsub;
            int l = l0 + row;
            if (l < LL) {
                int4v v = *(const int4v*)(hb + row*HBSTR + cpos*8);
                *(int4v*)(hout + (((size_t)(b*LL + l)) << 8) + half*128 + cpos*8) = v;
            }
        }
    }
    if (tid < 128) {
        int mt = tid >> 4, gg = (tid >> 2) & 3, rr = tid & 3;
        float s = 0.f, q = 0.f;
        #pragma unroll
        for (int wv = 0; wv < 4; ++wv) {
            s += redS[((wv*8 + mt)*4 + gg)*4 + rr];
            q += redQ[((wv*8 + mt)*4 + gg)*4 + rr];
        }
        int c = c0 + tid;
        int slot = b*NLT + ltile;
        psum[c*NPART + slot] = s;
        psq [c*NPART + slot] = q;
    }
}

// ---------------- k2: BN stats -> folded synthesis weights W3s[k][c] + SWS ----------------
__global__ __launch_bounds__(256)
void k2_bn(const float* __restrict__ psum, const float* __restrict__ psq,
           const float* __restrict__ bng, const float* __restrict__ bnb,
           const float* __restrict__ ctw, const float* __restrict__ ctg,
           const float* __restrict__ ctscale,
           float* __restrict__ W3s, float* __restrict__ SWS)
{
    __shared__ double rs[4], rq[4];
    __shared__ float s_a, s_bc;
    __shared__ float swl[256];
    const int c = blockIdx.x;
    const int tid = threadIdx.x;
    double s = 0.0, q = 0.0;
    for (int i = tid; i < NPART; i += 256) {
        s += (double)psum[c*NPART + i];
        q += (double)psq [c*NPART + i];
    }
    for (int off = 32; off > 0; off >>= 1) {
        s += __shfl_down(s, off);
        q += __shfl_down(q, off);
    }
    if ((tid & 63) == 0) { rs[tid >> 6] = s; rq[tid >> 6] = q; }
    __syncthreads();
    if (tid == 0) {
        double st = rs[0]+rs[1]+rs[2]+rs[3];
        double qt = rq[0]+rq[1]+rq[2]+rq[3];
        const double cnt = (double)BB * (double)LL;
        double mu = st / cnt;
        double var = qt / cnt - mu*mu;
        float rsig = (float)(1.0 / sqrt(var + 1e-5));
        float a = bng[c] * rsig;
        s_a = a;
        s_bc = bnb[c] - (float)mu * a;
    }
    __syncthreads();
    float a = s_a, bc = s_bc, scl = ctscale[0];
    int gi = c*KK + tid;                          // k = tid
    float wt = ctw[gi] * (ctg[gi] + 1.0f) * 0.5f;
    W3s[tid*KK + c] = scl * a * wt;
    swl[tid] = wt * bc;
    __syncthreads();
    if (tid < 16) {
        float acc2 = 0.0f;
        #pragma unroll
        for (int d = 0; d < 16; ++d) acc2 += swl[d*16 + tid];
        SWS[c*16 + tid] = acc2;
    }
}

__global__ void k2b_const(const float* __restrict__ SWS, const float* __restrict__ ctb,
                          const float* __restrict__ ctscale, float* __restrict__ C2)
{
    int r = threadIdx.x;
    if (r < 16) {
        float s = 0.0f;
        for (int c = 0; c < 256; ++c) s += SWS[c*16 + r];
        C2[r] = ctscale[0] * (s + ctb[0]);
    }
}

// ---------------- k2c: B2f fragment table for synthesis ----------------
__global__ void k2c_b2f(const float* __restrict__ W3s, unsigned short* __restrict__ B2f)
{
    int idx = blockIdx.x*256 + threadIdx.x;        // 38912 threads
    int lane = idx & 63;
    int ntG  = (idx>>6) & 3;
    int kk   = (idx>>8) & 7;
    int j    = idx>>11;
    int c    = kk*32 + ((lane>>4)<<3);
    int r    = lane & 15;
    int d    = ntG + 15 - j;
    short8 v;
    if (d >= 0 && d <= 15) {
        const float* wr = W3s + (size_t)(16*d + r)*KK + c;
        #pragma unroll
        for (int i = 0; i < 8; ++i) v[i] = (short)f2bf(wr[i]);
    } else {
        #pragma unroll
        for (int i = 0; i < 8; ++i) v[i] = 0;
    }
    *(short8*)(B2f + (size_t)idx*8) = v;
}

// ---------------- k3: synthesis conv, full-resident A window ----------------
// out[b][64P+u] = C2[u&15] + sum_{j,c} h[b][4P+1+j][c] * B2[(j,c)][u]
// 512 threads: all stage 272 rows (139264 B LDS); waves 0-3 compute (j-split); all reduce.
__global__ __launch_bounds__(512, 1)
void k3_synth(const unsigned short* __restrict__ h, const unsigned short* __restrict__ B2f,
              const float* __restrict__ C2, float* __restrict__ out)
{
    __shared__ __align__(16) char As[272*512];    // 139264 B; reduce buf aliases after compute
    const int tid  = threadIdx.x;
    const int lane = tid & 63;
    const int w    = tid >> 6;       // 0..7
    const int b    = blockIdx.y;
    const int P0   = blockIdx.x * 64;             // packed-P tile: 8 tiles x 64 = 512

    const unsigned short* hrow0 = h + (((size_t)(b*LL) + 4*P0 + 1) << 8);

    // ---- stage: rows w*34 .. w*34+33, XOR-swizzled chunk position ----
    {
        int4v tmp[17];
        #pragma unroll
        for (int i = 0; i < 17; ++i) {
            int r = w*34 + i*2 + (lane>>5);
            tmp[i] = *((const int4v*)(hrow0 + ((size_t)r << 8)) + (lane & 31));
        }
        #pragma unroll
        for (int i = 0; i < 17; ++i) {
            int r = w*34 + i*2 + (lane>>5);
            int p = (lane & 31) ^ ((r >> 2) & 7);
            *(int4v*)(As + r*512 + p*16) = tmp[i];
        }
    }
    __syncthreads();

    const bool cw = (w < 4);
    f32x4 acc[4][4];
    #pragma unroll
    for (int mt = 0; mt < 4; ++mt)
        #pragma unroll
        for (int nt = 0; nt < 4; ++nt) acc[mt][nt] = (f32x4){0.f,0.f,0.f,0.f};

    if (cw) {
        const int j0 = w*5;
        const int j1 = (w == 3) ? NJ : j0 + 5;
        for (int j = j0; j < j1; ++j) {
            #pragma unroll
            for (int kk = 0; kk < 8; ++kk) {
                short8 af[4], bfr[4];
                #pragma unroll
                for (int mt = 0; mt < 4; ++mt) {
                    int r = 64*mt + 4*(lane & 15) + j;
                    int p = (kk*4 + (lane >> 4)) ^ ((r >> 2) & 7);
                    af[mt] = *(const short8*)(As + r*512 + p*16);
                }
                #pragma unroll
                for (int nt = 0; nt < 4; ++nt)
                    bfr[nt] = *(const short8*)(B2f + (((size_t)(j*8 + kk)*4 + nt)*64 + lane)*8);
                #pragma unroll
                for (int mt = 0; mt < 4; ++mt)
                    #pragma unroll
                    for (int nt = 0; nt < 4; ++nt)
                        acc[mt][nt] = __builtin_amdgcn_mfma_f32_16x16x32_bf16(af[mt], bfr[nt], acc[mt][nt], 0, 0, 0);
            }
        }
    }
    __syncthreads();   // all compute reads of As done

    // ---- write partial accumulators: red[w][P_local][68] floats ----
    float* red = (float*)As;
    if (cw) {
        #pragma unroll
        for (int mt = 0; mt < 4; ++mt)
            #pragma unroll
            for (int nt = 0; nt < 4; ++nt) {
                int Pl = mt*16 + (lane >> 4)*4;
                int u  = nt*16 + (lane & 15);
                #pragma unroll
                for (int rr = 0; rr < 4; ++rr)
                    red[w*4352 + (Pl + rr)*68 + u] = acc[mt][nt][rr];
            }
    }
    __syncthreads();

    // ---- reduce 4 copies + C2, coalesced store ----
    {
        const float c2v = C2[tid & 15];
        const int u  = tid & 63;
        const int Pb = tid >> 6;         // 0..7
        float* ob = out + (size_t)b*TT + (size_t)P0*64;
        #pragma unroll
        for (int it = 0; it < 8; ++it) {
            int P = it*8 + Pb;
            float s = red[P*68 + u] + red[4352 + P*68 + u]
                    + red[8704 + P*68 + u] + red[13056 + P*68 + u];
            ob[P*64 + u] = s + c2v;
        }
    }
}

extern "C" void kernel_launch(void* const* d_in, const int* in_sizes, int n_in,
                              void* d_out, int out_size, void* d_ws, size_t ws_size,
                              hipStream_t stream)
{
    const float* x       = (const float*)d_in[0];
    const float* cw      = (const float*)d_in[1];
    const float* cb      = (const float*)d_in[2];
    const float* cgt     = (const float*)d_in[3];
    const float* cs      = (const float*)d_in[4];
    const float* bng     = (const float*)d_in[5];
    const float* bnb     = (const float*)d_in[6];
    const float* ctw     = (const float*)d_in[7];
    const float* ctb     = (const float*)d_in[8];
    const float* ctg     = (const float*)d_in[9];
    const float* ctscale = (const float*)d_in[10];
    float* out = (float*)d_out;

    char* ws = (char*)d_ws;
    size_t off = 0;
    unsigned short* h    = (unsigned short*)(ws + off); off += (size_t)BB*LL*KK*2;
    float* psum          = (float*)(ws + off);          off += (size_t)KK*NPART*4;
    float* psq           = (float*)(ws + off);          off += (size_t)KK*NPART*4;
    unsigned short* W1f  = (unsigned short*)(ws + off); off += 65536*2;
    float* W3s           = (float*)(ws + off);          off += (size_t)KK*KK*4;
    float* SWS           = (float*)(ws + off);          off += (size_t)KK*16*4;
    float* C2            = (float*)(ws + off);          off += 64;
    unsigned short* B2f  = (unsigned short*)(ws + off); off += (size_t)NJ*8*4*64*8*2;

    k0_w1f  <<<32, 256, 0, stream>>>(cw, cgt, W1f);
    k1_conv <<<dim3(18, BB), 256, 0, stream>>>(x, cs, cb, W1f, h, psum, psq);
    k2_bn   <<<KK, 256, 0, stream>>>(psum, psq, bng, bnb, ctw, ctg, ctscale, W3s, SWS);
    k2b_const<<<1, 64, 0, stream>>>(SWS, ctb, ctscale, C2);
    k2c_b2f <<<152, 256, 0, stream>>>(W3s, B2f);
    k3_synth<<<dim3(NPT, BB), 512, 0, stream>>>(h, B2f, C2, out);
}

// Round 7
// 106.999 us; speedup vs baseline: 6.6211x; 1.1597x over previous
//
#include <hip/hip_runtime.h>
#include <hip/hip_bf16.h>

#define BB 64
#define TT 32768
#define KK 256
#define LL 2065          // conv out length
#define NLT 9            // l-tiles of 256 per batch
#define NPART (BB*NLT)   // 576 partial slots per channel
#define NJ 19            // j-range for synthesis (P4 packing)
#define HBSTR 132        // k1 epilogue LDS row stride in ushorts (264 B)
#define NPT3 16          // k3 P-tiles per batch (32 packed positions each)

typedef __attribute__((ext_vector_type(8))) short short8;
typedef __attribute__((ext_vector_type(4))) float f32x4;
typedef __attribute__((ext_vector_type(4))) int int4v;
typedef __attribute__((ext_vector_type(2))) unsigned int uint2v;

__device__ __forceinline__ unsigned short f2bf(float f) {
    unsigned u = __builtin_bit_cast(unsigned, f);
    unsigned r = (u + 0x7FFFu + ((u >> 16) & 1u)) >> 16;
    return (unsigned short)r;
}
__device__ __forceinline__ unsigned pk2(float a, float b) {
    return (unsigned)f2bf(a) | ((unsigned)f2bf(b) << 16);
}
// async global->LDS, 16B per lane; lds dst = wave-uniform base + lane*16
__device__ __forceinline__ void gload_lds16(const void* g, void* l) {
    __builtin_amdgcn_global_load_lds(
        (const __attribute__((address_space(1))) unsigned int*)g,
        (__attribute__((address_space(3))) unsigned int*)l, 16, 0, 0);
}

// ---------------- k0: gated conv weights -> MFMA fragment-linear bf16 ----------------
__global__ void k0_w1f(const float* __restrict__ cw, const float* __restrict__ cgt,
                       unsigned short* __restrict__ W1f)
{
    int idx = blockIdx.x*256 + threadIdx.x;        // 8192 threads, 8 elems each
    int lane = idx & 63, ntL = (idx>>6)&7, kk = (idx>>9)&7, half = idx>>12;
    int o = half*128 + ntL*16 + (lane&15);
    int kbase = kk*32 + ((lane>>4)<<3);
    short8 v;
    #pragma unroll
    for (int i = 0; i < 8; ++i) {
        int gi = o*KK + kbase + i;
        v[i] = (short)f2bf(cw[gi]*(cgt[gi]+1.0f)*0.5f);
    }
    *(short8*)(W1f + (size_t)idx*8) = v;
}

// ---------------- k1: analysis conv (MFMA, swapped operands) ----------------
// acc holds h^T: lane owns c-quad (M-dim=c) at one l (N-dim=l).
__global__ __launch_bounds__(256, 2)
void k1_conv(const float* __restrict__ x, const float* __restrict__ cs,
             const float* __restrict__ cb, const unsigned short* __restrict__ W1f,
             unsigned short* __restrict__ hout,
             float* __restrict__ psum, float* __restrict__ psq)
{
    __shared__ __align__(16) char smem[13056 + 65536];   // 78592 B
    char* xwinb = smem;                      // padded bf16 x-window (13056 B)
    char* wbuf  = smem + 13056;              // W1f half (65536 B)
    // epilogue aliases:
    unsigned short* hb = (unsigned short*)smem;          // 256 x HBSTR ushorts = 67584 B
    float* redS = (float*)(smem + 67584);                // [4w][8mt][4g][4rr] = 2048 B
    float* redQ = (float*)(smem + 67584 + 2048);         // 71680 <= 78592 OK

    const int tid   = threadIdx.x;
    const int half  = blockIdx.x & 1;
    const int ltile = blockIdx.x >> 1;
    const int b     = blockIdx.y;
    const int l0    = ltile * 256;
    const long pos0 = (long)l0*16 - 256;
    const int lane  = tid & 63;
    const int w     = tid >> 6;

    // stage W1f half (64 KB) via global_load_lds: linear, no VGPR round-trip
    {
        const char* wsrc = (const char*)(W1f + (size_t)half*32768);
        #pragma unroll
        for (int it = 0; it < 16; ++it) {
            int off = w*16384 + it*1024;
            gload_lds16(wsrc + off + lane*16, wbuf + off);
        }
    }
    // stage x window: 272 groups of 16 elems; group g at bytes 48g..48g+31
    {
        const float* xs = x + (size_t)b*TT;
        for (int g = tid; g < 272; g += 256) {
            long base = pos0 + (long)g*16;
            unsigned uu[8];
            if (base >= 0 && base + 16 <= (long)TT) {
                const float4* xv = (const float4*)(xs + base);
                float4 a0 = xv[0], a1 = xv[1], a2 = xv[2], a3 = xv[3];
                uu[0] = pk2(a0.x, a0.y); uu[1] = pk2(a0.z, a0.w);
                uu[2] = pk2(a1.x, a1.y); uu[3] = pk2(a1.z, a1.w);
                uu[4] = pk2(a2.x, a2.y); uu[5] = pk2(a2.z, a2.w);
                uu[6] = pk2(a3.x, a3.y); uu[7] = pk2(a3.z, a3.w);
            } else {
                #pragma unroll
                for (int m = 0; m < 16; m += 2) {
                    long p = base + m;
                    float f0 = (p   >= 0 && p   < TT) ? xs[p]   : 0.0f;
                    float f1 = (p+1 >= 0 && p+1 < TT) ? xs[p+1] : 0.0f;
                    uu[m>>1] = pk2(f0, f1);
                }
            }
            int4v w0 = { (int)uu[0], (int)uu[1], (int)uu[2], (int)uu[3] };
            int4v w1 = { (int)uu[4], (int)uu[5], (int)uu[6], (int)uu[7] };
            *(int4v*)(xwinb + 48*g)      = w0;
            *(int4v*)(xwinb + 48*g + 16) = w1;
        }
    }
    __syncthreads();

    // K-loop: barrier-free. acc[mt=c-group 0..7][nt=l-group 0..3]
    f32x4 acc[8][4];
    #pragma unroll
    for (int mt = 0; mt < 8; ++mt)
        #pragma unroll
        for (int nt = 0; nt < 4; ++nt) acc[mt][nt] = (f32x4){0.f,0.f,0.f,0.f};

    const int gq = lane >> 4;
    const int Gt = 16*gq + 16*(gq>>1);                 // {0,16,48,64}
    const int abase = 48*((w<<6) + (lane & 15)) + Gt;  // + 768*nt + 96*kk

    #pragma unroll
    for (int kk = 0; kk < 8; ++kk) {
        short8 bfx[4];
        #pragma unroll
        for (int nt = 0; nt < 4; ++nt)
            bfx[nt] = *(const short8*)(xwinb + abase + nt*768 + kk*96);
        #pragma unroll
        for (int mt = 0; mt < 8; ++mt) {
            short8 afw = *(const short8*)(wbuf + (kk*8 + mt)*1024 + lane*16);
            #pragma unroll
            for (int nt = 0; nt < 4; ++nt)
                acc[mt][nt] = __builtin_amdgcn_mfma_f32_16x16x32_bf16(afw, bfx[nt], acc[mt][nt], 0, 0, 0);
        }
    }
    __syncthreads();   // xwin/wbuf dead; smem re-used as hb/redS/redQ

    // epilogue: scale/bias/relu; lane holds c-quad at one l -> b64 LDS writes
    const int c0 = half*128;
    const int g  = lane >> 4;
    const int li = lane & 15;
    for (int mt = 0; mt < 8; ++mt) {
        int cq = c0 + mt*16 + g*4;
        f32x4 cs4 = *(const f32x4*)&cs[cq];
        f32x4 cb4 = *(const f32x4*)&cb[cq];
        f32x4 s4 = (f32x4){0.f,0.f,0.f,0.f};
        f32x4 q4 = (f32x4){0.f,0.f,0.f,0.f};
        #pragma unroll
        for (int nt = 0; nt < 4; ++nt) {
            int lloc = (w<<6) + nt*16 + li;
            f32x4 hv;
            #pragma unroll
            for (int rr = 0; rr < 4; ++rr)
                hv[rr] = fmaxf(cs4[rr]*(acc[mt][nt][rr] + cb4[rr]), 0.0f);
            uint2v pkv = { pk2(hv[0], hv[1]), pk2(hv[2], hv[3]) };
            *(uint2v*)(hb + lloc*HBSTR + mt*16 + g*4) = pkv;
            if (l0 + lloc < LL) { s4 += hv; q4 += hv*hv; }
        }
        #pragma unroll
        for (int d = 1; d < 16; d <<= 1) {
            #pragma unroll
            for (int rr = 0; rr < 4; ++rr) {
                s4[rr] += __shfl_xor(s4[rr], d);
                q4[rr] += __shfl_xor(q4[rr], d);
            }
        }
        if (li == 0) {
            *(f32x4*)&redS[((w*8 + mt)*4 + g)*4] = s4;
            *(f32x4*)&redQ[((w*8 + mt)*4 + g)*4] = q4;
        }
    }
    __syncthreads();

    // coalesced h write: 16 lanes x 16B per row-half (256 B)
    {
        const int rsub = tid >> 4;       // 0..15
        const int cpos = tid & 15;
        #pragma unroll
        for (int it = 0; it < 16; ++it) {
            int row = it*16 + rsub;
            int l = l0 + row;
            if (l < LL) {
                int4v v = *(const int4v*)(hb + row*HBSTR + cpos*8);
                *(int4v*)(hout + (((size_t)(b*LL + l)) << 8) + half*128 + cpos*8) = v;
            }
        }
    }
    if (tid < 128) {
        int mt = tid >> 4, gg = (tid >> 2) & 3, rr = tid & 3;
        float s = 0.f, q = 0.f;
        #pragma unroll
        for (int wv = 0; wv < 4; ++wv) {
            s += redS[((wv*8 + mt)*4 + gg)*4 + rr];
            q += redQ[((wv*8 + mt)*4 + gg)*4 + rr];
        }
        int c = c0 + tid;
        int slot = b*NLT + ltile;
        psum[c*NPART + slot] = s;
        psq [c*NPART + slot] = q;
    }
}

// ---------------- k2: BN stats -> folded synthesis weights W3s[k][c] + SWS ----------------
__global__ __launch_bounds__(256)
void k2_bn(const float* __restrict__ psum, const float* __restrict__ psq,
           const float* __restrict__ bng, const float* __restrict__ bnb,
           const float* __restrict__ ctw, const float* __restrict__ ctg,
           const float* __restrict__ ctscale,
           float* __restrict__ W3s, float* __restrict__ SWS)
{
    __shared__ double rs[4], rq[4];
    __shared__ float s_a, s_bc;
    __shared__ float swl[256];
    const int c = blockIdx.x;
    const int tid = threadIdx.x;
    double s = 0.0, q = 0.0;
    for (int i = tid; i < NPART; i += 256) {
        s += (double)psum[c*NPART + i];
        q += (double)psq [c*NPART + i];
    }
    for (int off = 32; off > 0; off >>= 1) {
        s += __shfl_down(s, off);
        q += __shfl_down(q, off);
    }
    if ((tid & 63) == 0) { rs[tid >> 6] = s; rq[tid >> 6] = q; }
    __syncthreads();
    if (tid == 0) {
        double st = rs[0]+rs[1]+rs[2]+rs[3];
        double qt = rq[0]+rq[1]+rq[2]+rq[3];
        const double cnt = (double)BB * (double)LL;
        double mu = st / cnt;
        double var = qt / cnt - mu*mu;
        float rsig = (float)(1.0 / sqrt(var + 1e-5));
        float a = bng[c] * rsig;
        s_a = a;
        s_bc = bnb[c] - (float)mu * a;
    }
    __syncthreads();
    float a = s_a, bc = s_bc, scl = ctscale[0];
    int gi = c*KK + tid;                          // k = tid
    float wt = ctw[gi] * (ctg[gi] + 1.0f) * 0.5f;
    W3s[tid*KK + c] = scl * a * wt;
    swl[tid] = wt * bc;
    __syncthreads();
    if (tid < 16) {
        float acc2 = 0.0f;
        #pragma unroll
        for (int d = 0; d < 16; ++d) acc2 += swl[d*16 + tid];
        SWS[c*16 + tid] = acc2;
    }
}

__global__ void k2b_const(const float* __restrict__ SWS, const float* __restrict__ ctb,
                          const float* __restrict__ ctscale, float* __restrict__ C2)
{
    int r = threadIdx.x;
    if (r < 16) {
        float s = 0.0f;
        for (int c = 0; c < 256; ++c) s += SWS[c*16 + r];
        C2[r] = ctscale[0] * (s + ctb[0]);
    }
}

// ---------------- k2c: B2f fragment table for synthesis ----------------
__global__ void k2c_b2f(const float* __restrict__ W3s, unsigned short* __restrict__ B2f)
{
    int idx = blockIdx.x*256 + threadIdx.x;        // 38912 threads
    int lane = idx & 63;
    int ntG  = (idx>>6) & 3;
    int kk   = (idx>>8) & 7;
    int j    = idx>>11;
    int c    = kk*32 + ((lane>>4)<<3);
    int r    = lane & 15;
    int d    = ntG + 15 - j;
    short8 v;
    if (d >= 0 && d <= 15) {
        const float* wr = W3s + (size_t)(16*d + r)*KK + c;
        #pragma unroll
        for (int i = 0; i < 8; ++i) v[i] = (short)f2bf(wr[i]);
    } else {
        #pragma unroll
        for (int i = 0; i < 8; ++i) v[i] = 0;
    }
    *(short8*)(B2f + (size_t)idx*8) = v;
}

// ---------------- k3: synthesis conv, 32-P tiles, 2 blocks/CU, all waves compute ------
// out[b][64P+u] = C2[u&15] + sum_{j,c} h[b][4P+1+j][c] * B2[(j,c)][u]
// 256 threads: stage 144 rows (73728 B) via source-swizzled global_load_lds;
// 4 waves compute: wave = (pair-half, u-half); 2-copy LDS reduce.
__global__ __launch_bounds__(256, 2)
void k3_synth(const unsigned short* __restrict__ h, const unsigned short* __restrict__ B2f,
              const float* __restrict__ C2, float* __restrict__ out)
{
    __shared__ __align__(16) char As[144*512];    // 73728 B; red aliases after compute
    const int tid  = threadIdx.x;
    const int lane = tid & 63;
    const int w    = tid >> 6;       // 0..3
    const int b    = blockIdx.y;
    const int P0   = blockIdx.x * 32;

    const char* hbase = (const char*)h + (((size_t)(b*LL) + 4*P0 + 1) << 9);

    // ---- stage: 36 rows per wave, 2 rows per instr; source-chunk inverse-swizzled ----
    {
        const int rl = lane >> 5;                 // 0/1: row within pair
        #pragma unroll
        for (int i = 0; i < 18; ++i) {
            int r0  = w*36 + i*2;
            int row = r0 + rl;
            int chunk = (lane & 31) ^ ((row >> 2) & 7);
            gload_lds16(hbase + (size_t)row*512 + chunk*16, As + r0*512);
        }
    }
    __syncthreads();

    const int ph = w >> 1;           // (j,kk)-pair half
    const int uh = w & 1;            // u half
    f32x4 acc[2][2];
    #pragma unroll
    for (int mt = 0; mt < 2; ++mt)
        #pragma unroll
        for (int nt = 0; nt < 2; ++nt) acc[mt][nt] = (f32x4){0.f,0.f,0.f,0.f};

    const int li = lane & 15;
    #pragma unroll 4
    for (int i = 0; i < 76; ++i) {
        int t = ph*76 + i;
        int j = t >> 3, kk = t & 7;
        short8 af[2], bfr[2];
        #pragma unroll
        for (int mt = 0; mt < 2; ++mt) {
            int row = 64*mt + 4*li + j;
            int p = (kk*4 + (lane >> 4)) ^ ((row >> 2) & 7);
            af[mt] = *(const short8*)(As + row*512 + p*16);
        }
        #pragma unroll
        for (int nt = 0; nt < 2; ++nt) {
            int ntG = uh*2 + nt;
            bfr[nt] = *(const short8*)(B2f + (((size_t)(j*8 + kk)*4 + ntG)*64 + lane)*8);
        }
        #pragma unroll
        for (int mt = 0; mt < 2; ++mt)
            #pragma unroll
            for (int nt = 0; nt < 2; ++nt)
                acc[mt][nt] = __builtin_amdgcn_mfma_f32_16x16x32_bf16(af[mt], bfr[nt], acc[mt][nt], 0, 0, 0);
    }
    __syncthreads();   // all compute reads of As done

    // ---- partials: red[ph][P 0..31][68] ----
    float* red = (float*)As;
    #pragma unroll
    for (int mt = 0; mt < 2; ++mt)
        #pragma unroll
        for (int nt = 0; nt < 2; ++nt) {
            int Pl = mt*16 + (lane >> 4)*4;
            int u  = uh*32 + nt*16 + li;
            #pragma unroll
            for (int rr = 0; rr < 4; ++rr)
                red[ph*2176 + (Pl + rr)*68 + u] = acc[mt][nt][rr];
        }
    __syncthreads();

    // ---- reduce 2 copies + C2, coalesced store ----
    {
        const float c2v = C2[tid & 15];
        const int u  = tid & 63;
        const int Pb = tid >> 6;         // 0..3
        float* ob = out + (size_t)b*TT + (size_t)P0*64;
        #pragma unroll
        for (int it = 0; it < 8; ++it) {
            int P = it*4 + Pb;
            ob[P*64 + u] = red[P*68 + u] + red[2176 + P*68 + u] + c2v;
        }
    }
}

extern "C" void kernel_launch(void* const* d_in, const int* in_sizes, int n_in,
                              void* d_out, int out_size, void* d_ws, size_t ws_size,
                              hipStream_t stream)
{
    const float* x       = (const float*)d_in[0];
    const float* cw      = (const float*)d_in[1];
    const float* cb      = (const float*)d_in[2];
    const float* cgt     = (const float*)d_in[3];
    const float* cs      = (const float*)d_in[4];
    const float* bng     = (const float*)d_in[5];
    const float* bnb     = (const float*)d_in[6];
    const float* ctw     = (const float*)d_in[7];
    const float* ctb     = (const float*)d_in[8];
    const float* ctg     = (const float*)d_in[9];
    const float* ctscale = (const float*)d_in[10];
    float* out = (float*)d_out;

    char* ws = (char*)d_ws;
    size_t off = 0;
    unsigned short* h    = (unsigned short*)(ws + off); off += (size_t)BB*LL*KK*2;
    float* psum          = (float*)(ws + off);          off += (size_t)KK*NPART*4;
    float* psq           = (float*)(ws + off);          off += (size_t)KK*NPART*4;
    unsigned short* W1f  = (unsigned short*)(ws + off); off += 65536*2;
    float* W3s           = (float*)(ws + off);          off += (size_t)KK*KK*4;
    float* SWS           = (float*)(ws + off);          off += (size_t)KK*16*4;
    float* C2            = (float*)(ws + off);          off += 64;
    unsigned short* B2f  = (unsigned short*)(ws + off); off += (size_t)NJ*8*4*64*8*2;

    k0_w1f  <<<32, 256, 0, stream>>>(cw, cgt, W1f);
    k1_conv <<<dim3(18, BB), 256, 0, stream>>>(x, cs, cb, W1f, h, psum, psq);
    k2_bn   <<<KK, 256, 0, stream>>>(psum, psq, bng, bnb, ctw, ctg, ctscale, W3s, SWS);
    k2b_const<<<1, 64, 0, stream>>>(SWS, ctb, ctscale, C2);
    k2c_b2f <<<152, 256, 0, stream>>>(W3s, B2f);
    k3_synth<<<dim3(NPT3, BB), 256, 0, stream>>>(h, B2f, C2, out);
}